// Round 2
// 396.074 us; speedup vs baseline: 1.0213x; 1.0213x over previous
//
#include <hip/hip_runtime.h>
#include <stdint.h>

typedef __attribute__((ext_vector_type(4)))  int i32x4;
typedef __attribute__((ext_vector_type(16))) int i32x16;

#define M_TOK 8192
#define N_OUT 4096
#define K_IN  4096

// gemm geometry: 256x256 tile, BK = 64 i8 (64 B/row), 8 waves (2Mx4N),
// per-wave 128x64 output = 4x2 of mfma_i32_32x32x32_i8.
#define BM 256
#define BN 256
#define BKB 64            // bytes of K per tile
#define NT (K_IN / BKB)   // 64 K-tiles
#define SLOT_BYTES 32768  // A 16KB + B 16KB per slot
#define B_OFF 16384

// global->LDS direct copy, 16B per lane. LDS dest MUST be the wave-uniform
// base: HW writes lane L's 16B at (base + L*16). Per-lane gather is only
// allowed on the GLOBAL side.
#define GLDS16(gp, lp)                                                         \
  __builtin_amdgcn_global_load_lds(                                            \
      (const __attribute__((address_space(1))) void*)(gp),                     \
      (__attribute__((address_space(3))) void*)(lp), 16, 0, 0)

// ---------------------------------------------------------------------------
// x (fp32, row-major MxK) -> i8 with per-row scale. One block per row.
// ---------------------------------------------------------------------------
__global__ void __launch_bounds__(256) quant_x_i8(const float* __restrict__ x,
                                                  char* __restrict__ xq,
                                                  float* __restrict__ scales) {
  const int row = blockIdx.x;
  const int t   = threadIdx.x;
  const float4* rp = (const float4*)(x + (size_t)row * K_IN);

  float4 v[4];
#pragma unroll
  for (int p = 0; p < 4; p++) v[p] = rp[p * 256 + t];

  float amax = 0.f;
#pragma unroll
  for (int p = 0; p < 4; p++)
    amax = fmaxf(amax, fmaxf(fmaxf(fabsf(v[p].x), fabsf(v[p].y)),
                             fmaxf(fabsf(v[p].z), fabsf(v[p].w))));

#pragma unroll
  for (int off = 32; off > 0; off >>= 1)
    amax = fmaxf(amax, __shfl_xor(amax, off));

  __shared__ float wmax[4];
  if ((t & 63) == 0) wmax[t >> 6] = amax;
  __syncthreads();
  amax = fmaxf(fmaxf(wmax[0], wmax[1]), fmaxf(wmax[2], wmax[3]));
  amax = fmaxf(amax, 1e-30f);

  const float inv = 127.f / amax;
  if (t == 0) scales[row] = amax / 127.f;

  uint32_t* op = (uint32_t*)(xq + (size_t)row * K_IN);
#pragma unroll
  for (int p = 0; p < 4; p++) {
    uint32_t b0 = (uint32_t)(__float2int_rn(v[p].x * inv) & 0xFF);
    uint32_t b1 = (uint32_t)(__float2int_rn(v[p].y * inv) & 0xFF);
    uint32_t b2 = (uint32_t)(__float2int_rn(v[p].z * inv) & 0xFF);
    uint32_t b3 = (uint32_t)(__float2int_rn(v[p].w * inv) & 0xFF);
    op[p * 256 + t] = b0 | (b1 << 8) | (b2 << 16) | (b3 << 24);
  }
}

// ---------------------------------------------------------------------------
// sign(W) (fp32) -> i8 {-1,0,+1}.
// ---------------------------------------------------------------------------
__global__ void __launch_bounds__(256) quant_w_sign(const float* __restrict__ w,
                                                    char* __restrict__ wq) {
  const int t = threadIdx.x;
  const size_t base = (size_t)blockIdx.x * 1024;  // in float4 units
  const float4* p = (const float4*)w + base;
  uint32_t* op = (uint32_t*)wq + base;
#pragma unroll
  for (int q = 0; q < 4; q++) {
    float4 f = p[q * 256 + t];
    int s0 = (f.x > 0.f) - (f.x < 0.f);
    int s1 = (f.y > 0.f) - (f.y < 0.f);
    int s2 = (f.z > 0.f) - (f.z < 0.f);
    int s3 = (f.w > 0.f) - (f.w < 0.f);
    op[q * 256 + t] = (uint32_t)(s0 & 0xFF) | ((uint32_t)(s1 & 0xFF) << 8) |
                      ((uint32_t)(s2 & 0xFF) << 16) | ((uint32_t)(s3 & 0xFF) << 24);
  }
}

// ---------------------------------------------------------------------------
// C[m][n] = scale[m] * (sum_k Aq[m][k] * Wq[n][k]) + bias[n]
//
// Pipelined schedule (T3+T4+T5): 4 LDS slots, prefetch distance 3.
// Iteration t:  s_waitcnt vmcnt(8)   <- own tile-t loads done; t+1,t+2 in flight
//               s_barrier            <- ALL waves' tile-t loads landed AND all
//                                       reads of tile t-1 are register-complete
//               sched_barrier(0)     <- no code motion across the barrier
//               stage tile t+3       <- into slot of tile t-1 (WAR-safe)
//               compute tile t       <- ds_read + 16 MFMA, setprio around MFMA
// vmcnt never drains to 0 until the last two iterations.
//
// LDS swizzle: row r (64B = 4 chunks of 16B) stores chunk c at slot
// c ^ ((r>>1)&3). Staged linearly by global_load_lds (lane L -> byte L*16
// after wave base): lane L covers row (L>>2), slot L&3, so the GLOBAL source
// chunk is (L&3) ^ ((L>>3)&3). Fragment ds_read_b128 (lane L: row L&31,
// chunk 2ks+(L>>5)) then spreads every 8 rows over all 32 banks.
// ---------------------------------------------------------------------------
__global__ void __launch_bounds__(512, 2) gemm_bin_i8(
    const char* __restrict__ A, const char* __restrict__ B,
    const float* __restrict__ scales, const float* __restrict__ bias,
    float* __restrict__ C) {
  __shared__ __align__(16) char lds[4 * SLOT_BYTES];  // 128 KB

  const int tid  = threadIdx.x;
  const int lane = tid & 63;
  const int wv   = tid >> 6;   // 0..7
  const int wm   = wv >> 2;    // 0..1  (M half)
  const int wn   = wv & 3;     // 0..3  (N quarter)

  // XCD-aware bijective swizzle: 512 blocks, 8 XCDs, 64 per XCD chunk.
  int bid = (int)blockIdx.x;
  bid = (bid & 7) * (512 >> 3) + (bid >> 3);
  const int m0 = (bid >> 4) * BM;  // 32 m-tiles
  const int n0 = (bid & 15) * BN;  // 16 n-tiles

  // ---- staging: wave wv stages rows [wv*32, wv*32+32) of A and B,
  // 2 GLDS16 each (16 rows / 1024 B per instruction).
  const int srow   = lane >> 2;                       // 0..15
  const int schunk = (lane & 3) ^ ((lane >> 3) & 3);  // pre-swizzled source chunk
  const char* gAb = A + (size_t)(m0 + wv * 32 + srow) * K_IN + schunk * 16;
  const char* gBb = B + (size_t)(n0 + wv * 32 + srow) * K_IN + schunk * 16;
  // WAVE-UNIFORM LDS bases (HW adds lane*16 itself).
  char* lAb = lds + wv * 2048;
  char* lBb = lds + B_OFF + wv * 2048;

  auto stage = [&](int tt, int sl) {
    const size_t ko = (size_t)tt * BKB;
    GLDS16(gAb + ko,                     lAb + sl * SLOT_BYTES);
    GLDS16(gAb + ko + (size_t)16 * K_IN, lAb + sl * SLOT_BYTES + 1024);
    GLDS16(gBb + ko,                     lBb + sl * SLOT_BYTES);
    GLDS16(gBb + ko + (size_t)16 * K_IN, lBb + sl * SLOT_BYTES + 1024);
  };

  // ---- fragment read constants
  const int fr  = lane & 31;         // row within 32-row subtile
  const int k16 = lane >> 5;         // which 16B half of the 32-i8 k-slice
  const int x3  = (lane >> 1) & 3;   // swizzle term ((row>>1)&3)
  const int aoff = wm * 8192 + fr * 64;           // wm*128 rows
  const int boff = B_OFF + wn * 4096 + fr * 64;   // wn*64 rows

  i32x16 acc[4][2];
#pragma unroll
  for (int m = 0; m < 4; m++)
#pragma unroll
    for (int n = 0; n < 2; n++)
#pragma unroll
      for (int r = 0; r < 16; r++) acc[m][n][r] = 0;

  auto compute = [&](int sl) {
    const char* pA = lds + sl * SLOT_BYTES + aoff;
    const char* pB = lds + sl * SLOT_BYTES + boff;
#pragma unroll
    for (int ks = 0; ks < 2; ks++) {
      const int so = ((2 * ks + k16) ^ x3) << 4;
      i32x4 a0 = *(const i32x4*)(pA + so);
      i32x4 a1 = *(const i32x4*)(pA + 2048 + so);
      i32x4 a2 = *(const i32x4*)(pA + 4096 + so);
      i32x4 a3 = *(const i32x4*)(pA + 6144 + so);
      i32x4 b0 = *(const i32x4*)(pB + so);
      i32x4 b1 = *(const i32x4*)(pB + 2048 + so);
      __builtin_amdgcn_s_setprio(1);
      acc[0][0] = __builtin_amdgcn_mfma_i32_32x32x32_i8(a0, b0, acc[0][0], 0, 0, 0);
      acc[0][1] = __builtin_amdgcn_mfma_i32_32x32x32_i8(a0, b1, acc[0][1], 0, 0, 0);
      acc[1][0] = __builtin_amdgcn_mfma_i32_32x32x32_i8(a1, b0, acc[1][0], 0, 0, 0);
      acc[1][1] = __builtin_amdgcn_mfma_i32_32x32x32_i8(a1, b1, acc[1][1], 0, 0, 0);
      acc[2][0] = __builtin_amdgcn_mfma_i32_32x32x32_i8(a2, b0, acc[2][0], 0, 0, 0);
      acc[2][1] = __builtin_amdgcn_mfma_i32_32x32x32_i8(a2, b1, acc[2][1], 0, 0, 0);
      acc[3][0] = __builtin_amdgcn_mfma_i32_32x32x32_i8(a3, b0, acc[3][0], 0, 0, 0);
      acc[3][1] = __builtin_amdgcn_mfma_i32_32x32x32_i8(a3, b1, acc[3][1], 0, 0, 0);
      __builtin_amdgcn_s_setprio(0);
    }
  };

  // ---- prologue: stage tiles 0,1,2 into slots 0,1,2 (12 loads in flight)
  stage(0, 0);
  stage(1, 1);
  stage(2, 2);

  // ---- main loop: counted vmcnt, one barrier per K-tile, prefetch dist 3
  for (int t = 0; t < NT - 3; ++t) {
    asm volatile("s_waitcnt vmcnt(8)" ::: "memory");  // tile t landed; t+1,t+2 fly
    __builtin_amdgcn_s_barrier();
    __builtin_amdgcn_sched_barrier(0);
    stage(t + 3, (t + 3) & 3);
    compute(t & 3);
  }
  asm volatile("s_waitcnt vmcnt(8)" ::: "memory");
  __builtin_amdgcn_s_barrier();
  __builtin_amdgcn_sched_barrier(0);
  compute((NT - 3) & 3);
  asm volatile("s_waitcnt vmcnt(4)" ::: "memory");
  __builtin_amdgcn_s_barrier();
  __builtin_amdgcn_sched_barrier(0);
  compute((NT - 2) & 3);
  asm volatile("s_waitcnt vmcnt(0)" ::: "memory");
  __builtin_amdgcn_s_barrier();
  __builtin_amdgcn_sched_barrier(0);
  compute((NT - 1) & 3);

  // ---- epilogue: 32x32 C/D layout col=lane&31, row=(r&3)+8*(r>>2)+4*(lane>>5)
  const int col0 = n0 + wn * 64 + (lane & 31);
  const float bv0 = bias[col0];
  const float bv1 = bias[col0 + 32];
#pragma unroll
  for (int m = 0; m < 4; m++) {
    const int rb = m0 + wm * 128 + m * 32 + ((lane >> 5) << 2);
#pragma unroll
    for (int r = 0; r < 16; r++) {
      const int row = rb + (r & 3) + ((r >> 2) << 3);
      const float sc = scales[row];
      float* cp = C + (size_t)row * N_OUT + col0;
      cp[0]  = (float)acc[m][0][r] * sc + bv0;
      cp[32] = (float)acc[m][1][r] * sc + bv1;
    }
  }
}

// emergency fallback if ws too small (correct but slow)
__global__ void fallback_gemm(const float* __restrict__ x, const float* __restrict__ w,
                              const float* __restrict__ bias, float* __restrict__ out) {
  int idx = blockIdx.x * blockDim.x + threadIdx.x;
  if (idx >= M_TOK * N_OUT) return;
  int row = idx / N_OUT, col = idx % N_OUT;
  const float* xp = x + (size_t)row * K_IN;
  const float* wp = w + (size_t)col * K_IN;
  float s = 0.f;
  for (int k = 0; k < K_IN; k++) {
    float wv = wp[k];
    float sg = wv > 0.f ? 1.f : (wv < 0.f ? -1.f : 0.f);
    s += xp[k] * sg;
  }
  out[idx] = s + bias[col];
}

extern "C" void kernel_launch(void* const* d_in, const int* in_sizes, int n_in,
                              void* d_out, int out_size, void* d_ws, size_t ws_size,
                              hipStream_t stream) {
  const float* x    = (const float*)d_in[0];
  const float* w    = (const float*)d_in[1];
  const float* bias = (const float*)d_in[2];
  float* out = (float*)d_out;

  const size_t xq_bytes = (size_t)M_TOK * K_IN;           // 32 MiB
  const size_t wq_bytes = (size_t)N_OUT * K_IN;           // 16 MiB
  const size_t sc_bytes = (size_t)M_TOK * sizeof(float);  // 32 KiB

  if (ws_size < xq_bytes + wq_bytes + sc_bytes) {
    int total = M_TOK * N_OUT;
    fallback_gemm<<<(total + 255) / 256, 256, 0, stream>>>(x, w, bias, out);
    return;
  }

  char*  xq = (char*)d_ws;
  char*  wq = (char*)d_ws + xq_bytes;
  float* sc = (float*)((char*)d_ws + xq_bytes + wq_bytes);

  quant_x_i8<<<M_TOK, 256, 0, stream>>>(x, xq, sc);
  quant_w_sign<<<(N_OUT * K_IN / 4) / 1024, 256, 0, stream>>>(w, wq);

  // 32 x 16 = 512 blocks of 512 threads (8 waves), 128 KB LDS -> 1 block/CU
  gemm_bin_i8<<<512, 512, 0, stream>>>(xq, wq, sc, bias, out);
}